// Round 3
// baseline (191.041 us; speedup 1.0000x reference)
//
#include <hip/hip_runtime.h>
#include <hip/hip_bf16.h>
#include <stdint.h>

#define KD 256
#define NPIX 131072
#define NCM 190
#define CMP 192
#define LAMBDA 0.00390625f
#define LN_EPS 1e-5f
#define TM 32  // pixel rows per block

typedef __attribute__((ext_vector_type(4))) float f32x4;
typedef __attribute__((ext_vector_type(8))) short bf16x8;

__device__ __forceinline__ float wred64(float v) {
#pragma unroll
  for (int off = 32; off > 0; off >>= 1) v += __shfl_xor(v, off, 64);
  return v;
}

__device__ __forceinline__ float wred16(float v) {
#pragma unroll
  for (int off = 8; off > 0; off >>= 1) v += __shfl_xor(v, off, 64);
  return v;
}

// round-to-nearest-even f32 -> bf16 bits
__device__ __forceinline__ ushort f2bf(float f) {
  uint32_t u = __float_as_uint(f);
  u += 0x7FFFu + ((u >> 16) & 1u);
  return (ushort)(u >> 16);
}

// ---------------- kernel 1: prototype-side prep (tiny) ----------------
// Builds B' [192][512] bf16:  cols 0..255  = 2 * pbar[cm][k]
//                              cols 256..511 = (2/K) * sqrt(proto_var[cm][k])
// and spc[cm] = 2 + (1/K) * sum_k proto_var[cm][k]
__global__ __launch_bounds__(256) void proto_prep_kernel(
    const float* __restrict__ protos, const float* __restrict__ pvar,
    const float* __restrict__ gam, const float* __restrict__ bet,
    const float* __restrict__ eps_p,
    ushort* __restrict__ Bp, float* __restrict__ spc) {
  const int wave = threadIdx.x >> 6;
  const int lane = threadIdx.x & 63;
  const int cm = blockIdx.x * 4 + wave;
  if (cm >= CMP) return;
  ushort* row = Bp + (size_t)cm * 512;
  if (cm >= NCM) {  // zero pad rows 190,191
    for (int j = lane; j < 512; j += 64) row[j] = 0;
    if (lane == 0) spc[cm] = 0.f;
    return;
  }
  const int k0 = lane * 4;
  f32x4 pv = *(const f32x4*)(pvar + (size_t)cm * KD + k0);
  f32x4 pm = *(const f32x4*)(protos + (size_t)cm * KD + k0);
  f32x4 gg = *(const f32x4*)(gam + k0);
  f32x4 bb = *(const f32x4*)(bet + k0);
  float spv = wred64(pv.x + pv.y + pv.z + pv.w);
  f32x4 acc = {0.f, 0.f, 0.f, 0.f};
#pragma unroll
  for (int r = 0; r < 2; ++r) {
    f32x4 e = *(const f32x4*)(eps_p + ((size_t)r * NCM + cm) * KD + k0);
    f32x4 v;
    v.x = e.x * pv.x + pm.x;
    v.y = e.y * pv.y + pm.y;
    v.z = e.z * pv.z + pm.z;
    v.w = e.w * pv.w + pm.w;
    float s1 = wred64(v.x + v.y + v.z + v.w);
    float s2 = wred64(v.x * v.x + v.y * v.y + v.z * v.z + v.w * v.w);
    float mean = s1 * (1.f / KD);
    float var = s2 * (1.f / KD) - mean * mean;
    float rs = rsqrtf(var + LN_EPS);
    f32x4 y;
    y.x = (v.x - mean) * rs * gg.x + bb.x;
    y.y = (v.y - mean) * rs * gg.y + bb.y;
    y.z = (v.z - mean) * rs * gg.z + bb.z;
    y.w = (v.w - mean) * rs * gg.w + bb.w;
    float n2 = wred64(y.x * y.x + y.y * y.y + y.z * y.z + y.w * y.w);
    float inv = 1.f / fmaxf(sqrtf(n2), 1e-12f);
    acc.x += y.x * inv;
    acc.y += y.y * inv;
    acc.z += y.z * inv;
    acc.w += y.w * inv;
  }
  // 2 * pbar = 2 * (acc/2) = acc
  row[k0 + 0] = f2bf(acc.x);
  row[k0 + 1] = f2bf(acc.y);
  row[k0 + 2] = f2bf(acc.z);
  row[k0 + 3] = f2bf(acc.w);
  const float s = 2.f * LAMBDA;
  row[256 + k0 + 0] = f2bf(s * sqrtf(pv.x));
  row[256 + k0 + 1] = f2bf(s * sqrtf(pv.y));
  row[256 + k0 + 2] = f2bf(s * sqrtf(pv.z));
  row[256 + k0 + 3] = f2bf(s * sqrtf(pv.w));
  if (lane == 0) spc[cm] = 2.f + LAMBDA * spv;
}

// ---------------- kernel 2: fused pixel prep + GEMM + epilogue ----------------
// block = 256 thr (4 waves), TM=32 pixel rows/block, 4 blocks/CU.
// Phase A: 16-lanes-per-row; wave w preprocesses rows 8w..8w+7 (2 groups of 4
//          concurrent rows) into swizzled LDS A [32][512] bf16
//          (first 256 = xbar, last 256 = sqrt(x_var)); sxl[m] = lambda*sum(x_var).
// Phase B: 16x16x32 bf16 MFMA, A[32][512] x B'[512][192]; wave w owns cols 48w..48w+47.
// Epilogue: stage out tile in LDS (reusing A), coalesced float2 copy.
__global__ __launch_bounds__(256, 4) void fused_main_kernel(
    const float* __restrict__ x, const float* __restrict__ xvar,
    const float* __restrict__ gam, const float* __restrict__ bet,
    const float* __restrict__ eps_x,
    const ushort* __restrict__ Bp, const float* __restrict__ spc,
    float* __restrict__ out) {
  __shared__ ushort As[TM * 512];
  __shared__ float sxl[TM];
  const int tid = threadIdx.x;
  const int wave = tid >> 6;
  const int lane = tid & 63;
  const int64_t nbase = (int64_t)blockIdx.x * TM;

  // ---------------- Phase A ----------------
  const int sub = lane >> 4;  // row within group of 4
  const int l = lane & 15;    // 16 lanes per row, 16 elems each
  f32x4 gg[4], bb[4];
#pragma unroll
  for (int j = 0; j < 4; ++j) {
    gg[j] = *(const f32x4*)(gam + l * 16 + 4 * j);
    bb[j] = *(const f32x4*)(bet + l * 16 + 4 * j);
  }

  for (int g = 0; g < 2; ++g) {
    const int m = wave * 8 + g * 4 + sub;
    const int64_t n = nbase + m;
    const float* px = x + n * KD + l * 16;
    const float* pxv = xvar + n * KD + l * 16;
    f32x4 xm[4], xv[4];
#pragma unroll
    for (int j = 0; j < 4; ++j) {
      xm[j] = *(const f32x4*)(px + 4 * j);
      xv[j] = *(const f32x4*)(pxv + 4 * j);
    }
    float sxv = 0.f;
#pragma unroll
    for (int j = 0; j < 4; ++j) sxv += xv[j].x + xv[j].y + xv[j].z + xv[j].w;
    sxv = wred16(sxv);

    f32x4 acc[4];
#pragma unroll
    for (int j = 0; j < 4; ++j) acc[j] = (f32x4){0.f, 0.f, 0.f, 0.f};

#pragma unroll
    for (int r = 0; r < 2; ++r) {
      const float* pe = eps_x + ((int64_t)r * NPIX + n) * KD + l * 16;
      f32x4 v[4];
      float s1 = 0.f, s2 = 0.f;
#pragma unroll
      for (int j = 0; j < 4; ++j) {
        f32x4 e = *(const f32x4*)(pe + 4 * j);
        v[j].x = e.x * xv[j].x + xm[j].x;
        v[j].y = e.y * xv[j].y + xm[j].y;
        v[j].z = e.z * xv[j].z + xm[j].z;
        v[j].w = e.w * xv[j].w + xm[j].w;
        s1 += v[j].x + v[j].y + v[j].z + v[j].w;
        s2 += v[j].x * v[j].x + v[j].y * v[j].y + v[j].z * v[j].z + v[j].w * v[j].w;
      }
      s1 = wred16(s1);
      s2 = wred16(s2);
      float mean = s1 * (1.f / KD);
      float var = s2 * (1.f / KD) - mean * mean;
      float rs = rsqrtf(var + LN_EPS);
      float n2 = 0.f;
      f32x4 y[4];
#pragma unroll
      for (int j = 0; j < 4; ++j) {
        y[j].x = (v[j].x - mean) * rs * gg[j].x + bb[j].x;
        y[j].y = (v[j].y - mean) * rs * gg[j].y + bb[j].y;
        y[j].z = (v[j].z - mean) * rs * gg[j].z + bb[j].z;
        y[j].w = (v[j].w - mean) * rs * gg[j].w + bb[j].w;
        n2 += y[j].x * y[j].x + y[j].y * y[j].y + y[j].z * y[j].z + y[j].w * y[j].w;
      }
      n2 = wred16(n2);
      float inv = 1.f / fmaxf(sqrtf(n2), 1e-12f);
#pragma unroll
      for (int j = 0; j < 4; ++j) {
        acc[j].x += y[j].x * inv;
        acc[j].y += y[j].y * inv;
        acc[j].z += y[j].z * inv;
        acc[j].w += y[j].w * inv;
      }
    }

    // pack to bf16 and write swizzled LDS row m
    char* rowp = (char*)As + m * 1024;
    const int sw = (m & 7) << 4;
    union {
      uint4 q;
      ushort s[8];
    } pk;
    // xbar half (scale 0.5 = mean over R=2)
    pk.s[0] = f2bf(0.5f * acc[0].x);
    pk.s[1] = f2bf(0.5f * acc[0].y);
    pk.s[2] = f2bf(0.5f * acc[0].z);
    pk.s[3] = f2bf(0.5f * acc[0].w);
    pk.s[4] = f2bf(0.5f * acc[1].x);
    pk.s[5] = f2bf(0.5f * acc[1].y);
    pk.s[6] = f2bf(0.5f * acc[1].z);
    pk.s[7] = f2bf(0.5f * acc[1].w);
    *(uint4*)(rowp + ((l * 32) ^ sw)) = pk.q;
    pk.s[0] = f2bf(0.5f * acc[2].x);
    pk.s[1] = f2bf(0.5f * acc[2].y);
    pk.s[2] = f2bf(0.5f * acc[2].z);
    pk.s[3] = f2bf(0.5f * acc[2].w);
    pk.s[4] = f2bf(0.5f * acc[3].x);
    pk.s[5] = f2bf(0.5f * acc[3].y);
    pk.s[6] = f2bf(0.5f * acc[3].z);
    pk.s[7] = f2bf(0.5f * acc[3].w);
    *(uint4*)(rowp + ((l * 32 + 16) ^ sw)) = pk.q;
    // sqrt(x_var) half
    pk.s[0] = f2bf(sqrtf(xv[0].x));
    pk.s[1] = f2bf(sqrtf(xv[0].y));
    pk.s[2] = f2bf(sqrtf(xv[0].z));
    pk.s[3] = f2bf(sqrtf(xv[0].w));
    pk.s[4] = f2bf(sqrtf(xv[1].x));
    pk.s[5] = f2bf(sqrtf(xv[1].y));
    pk.s[6] = f2bf(sqrtf(xv[1].z));
    pk.s[7] = f2bf(sqrtf(xv[1].w));
    *(uint4*)(rowp + ((512 + l * 32) ^ sw)) = pk.q;
    pk.s[0] = f2bf(sqrtf(xv[2].x));
    pk.s[1] = f2bf(sqrtf(xv[2].y));
    pk.s[2] = f2bf(sqrtf(xv[2].z));
    pk.s[3] = f2bf(sqrtf(xv[2].w));
    pk.s[4] = f2bf(sqrtf(xv[3].x));
    pk.s[5] = f2bf(sqrtf(xv[3].y));
    pk.s[6] = f2bf(sqrtf(xv[3].z));
    pk.s[7] = f2bf(sqrtf(xv[3].w));
    *(uint4*)(rowp + ((512 + l * 32 + 16) ^ sw)) = pk.q;
    if (l == 0) sxl[m] = LAMBDA * sxv;
  }
  __syncthreads();

  // ---------------- Phase B: MFMA ----------------
  f32x4 acc[2][3];
#pragma unroll
  for (int s = 0; s < 2; ++s)
#pragma unroll
    for (int t = 0; t < 3; ++t) acc[s][t] = (f32x4){0.f, 0.f, 0.f, 0.f};

  const int colq = lane & 15;
  const int kq = lane >> 4;
  const int colbase = wave * 48;
#pragma unroll
  for (int kk = 0; kk < 16; ++kk) {
    const int kbyte = kk * 64 + kq * 16;
    bf16x8 af[2];
#pragma unroll
    for (int s = 0; s < 2; ++s) {
      const int m = s * 16 + colq;
      af[s] = *(const bf16x8*)((const char*)As + m * 1024 + (kbyte ^ ((m & 7) << 4)));
    }
#pragma unroll
    for (int t = 0; t < 3; ++t) {
      const int cmc = colbase + t * 16 + colq;
      bf16x8 bfr = *(const bf16x8*)((const char*)Bp + (size_t)cmc * 1024 + kbyte);
#pragma unroll
      for (int s = 0; s < 2; ++s)
        acc[s][t] = __builtin_amdgcn_mfma_f32_16x16x32_bf16(af[s], bfr, acc[s][t], 0, 0, 0);
    }
  }
  __syncthreads();  // all As reads done before reuse

  // ---------------- Epilogue: stage in LDS, coalesced copy ----------------
  float* st = (float*)As;  // 32*190 floats = 24320 B <= 32 KB
#pragma unroll
  for (int t = 0; t < 3; ++t) {
    const int col = colbase + t * 16 + colq;
    if (col < NCM) {
      const float sc = spc[col];
#pragma unroll
      for (int s = 0; s < 2; ++s) {
#pragma unroll
        for (int j = 0; j < 4; ++j) {
          const int m = s * 16 + kq * 4 + j;
          st[m * NCM + col] = acc[s][t][j] - sc - sxl[m];
        }
      }
    }
  }
  __syncthreads();
  const float2* src = (const float2*)st;
  float2* dst = (float2*)(out + nbase * NCM);
#pragma unroll
  for (int i = tid; i < TM * NCM / 2; i += 256) dst[i] = src[i];
}

extern "C" void kernel_launch(void* const* d_in, const int* in_sizes, int n_in,
                              void* d_out, int out_size, void* d_ws, size_t ws_size,
                              hipStream_t stream) {
  const float* x = (const float*)d_in[0];
  const float* x_var = (const float*)d_in[1];
  const float* protos = (const float*)d_in[2];
  const float* pvar = (const float*)d_in[3];
  const float* gam = (const float*)d_in[4];
  const float* bet = (const float*)d_in[5];
  const float* eps_x = (const float*)d_in[6];
  const float* eps_p = (const float*)d_in[7];
  float* out = (float*)d_out;

  ushort* Bp = (ushort*)d_ws;                          // 192*512*2 = 196608 B
  float* spc = (float*)((char*)d_ws + CMP * 512 * 2);  // 192*4 B

  proto_prep_kernel<<<CMP / 4, 256, 0, stream>>>(protos, pvar, gam, bet, eps_p, Bp, spc);
  fused_main_kernel<<<NPIX / TM, 256, 0, stream>>>(x, x_var, gam, bet, eps_x, Bp, spc, out);
}

// Round 6
// 188.706 us; speedup vs baseline: 1.0124x; 1.0124x over previous
//
#include <hip/hip_runtime.h>
#include <hip/hip_bf16.h>
#include <stdint.h>

#define KD 256
#define NPIX 131072
#define NCM 190
#define CMP 192
#define LAMBDA 0.00390625f
#define LN_EPS 1e-5f
#define TM 32  // pixel rows per block

typedef __attribute__((ext_vector_type(4))) float f32x4;
typedef __attribute__((ext_vector_type(8))) short bf16x8;

__device__ __forceinline__ float wred64(float v) {
#pragma unroll
  for (int off = 32; off > 0; off >>= 1) v += __shfl_xor(v, off, 64);
  return v;
}

__device__ __forceinline__ float wred16(float v) {
#pragma unroll
  for (int off = 8; off > 0; off >>= 1) v += __shfl_xor(v, off, 64);
  return v;
}

// round-to-nearest-even f32 -> bf16 bits
__device__ __forceinline__ ushort f2bf(float f) {
  uint32_t u = __float_as_uint(f);
  u += 0x7FFFu + ((u >> 16) & 1u);
  return (ushort)(u >> 16);
}

// ---------------- kernel 1: prototype-side prep (tiny) ----------------
// Builds B' [192][512] bf16:  cols 0..255  = 2 * pbar[cm][k]
//                              cols 256..511 = (2/K) * sqrt(proto_var[cm][k])
// and spc[cm] = 2 + (1/K) * sum_k proto_var[cm][k]
__global__ __launch_bounds__(256) void proto_prep_kernel(
    const float* __restrict__ protos, const float* __restrict__ pvar,
    const float* __restrict__ gam, const float* __restrict__ bet,
    const float* __restrict__ eps_p,
    ushort* __restrict__ Bp, float* __restrict__ spc) {
  const int wave = threadIdx.x >> 6;
  const int lane = threadIdx.x & 63;
  const int cm = blockIdx.x * 4 + wave;
  if (cm >= CMP) return;
  ushort* row = Bp + (size_t)cm * 512;
  if (cm >= NCM) {  // zero pad rows 190,191
    for (int j = lane; j < 512; j += 64) row[j] = 0;
    if (lane == 0) spc[cm] = 0.f;
    return;
  }
  const int k0 = lane * 4;
  f32x4 pv = *(const f32x4*)(pvar + (size_t)cm * KD + k0);
  f32x4 pm = *(const f32x4*)(protos + (size_t)cm * KD + k0);
  f32x4 gg = *(const f32x4*)(gam + k0);
  f32x4 bb = *(const f32x4*)(bet + k0);
  float spv = wred64(pv.x + pv.y + pv.z + pv.w);
  f32x4 acc = {0.f, 0.f, 0.f, 0.f};
#pragma unroll
  for (int r = 0; r < 2; ++r) {
    f32x4 e = *(const f32x4*)(eps_p + ((size_t)r * NCM + cm) * KD + k0);
    f32x4 v;
    v.x = e.x * pv.x + pm.x;
    v.y = e.y * pv.y + pm.y;
    v.z = e.z * pv.z + pm.z;
    v.w = e.w * pv.w + pm.w;
    float s1 = wred64(v.x + v.y + v.z + v.w);
    float s2 = wred64(v.x * v.x + v.y * v.y + v.z * v.z + v.w * v.w);
    float mean = s1 * (1.f / KD);
    float var = s2 * (1.f / KD) - mean * mean;
    float rs = rsqrtf(var + LN_EPS);
    f32x4 y;
    y.x = (v.x - mean) * rs * gg.x + bb.x;
    y.y = (v.y - mean) * rs * gg.y + bb.y;
    y.z = (v.z - mean) * rs * gg.z + bb.z;
    y.w = (v.w - mean) * rs * gg.w + bb.w;
    float n2 = wred64(y.x * y.x + y.y * y.y + y.z * y.z + y.w * y.w);
    float inv = 1.f / fmaxf(sqrtf(n2), 1e-12f);
    acc.x += y.x * inv;
    acc.y += y.y * inv;
    acc.z += y.z * inv;
    acc.w += y.w * inv;
  }
  // 2 * pbar = 2 * (acc/2) = acc
  row[k0 + 0] = f2bf(acc.x);
  row[k0 + 1] = f2bf(acc.y);
  row[k0 + 2] = f2bf(acc.z);
  row[k0 + 3] = f2bf(acc.w);
  const float s = 2.f * LAMBDA;
  row[256 + k0 + 0] = f2bf(s * sqrtf(pv.x));
  row[256 + k0 + 1] = f2bf(s * sqrtf(pv.y));
  row[256 + k0 + 2] = f2bf(s * sqrtf(pv.z));
  row[256 + k0 + 3] = f2bf(s * sqrtf(pv.w));
  if (lane == 0) spc[cm] = 2.f + LAMBDA * spv;
}

// ---------------- kernel 2: fused pixel prep + GEMM + epilogue ----------------
// block = 256 thr (4 waves), TM=32 pixel rows/block, 4 blocks/CU.
// Phase A: 16-lanes-per-row; wave w preprocesses rows 8w..8w+7 (2 groups of 4
//          concurrent rows). eps loads for BOTH r issued at group top so r=1's
//          data is in flight under r=0's reduction chain. Math is bit-identical
//          to the verified TM=32 kernel (same element mapping l*16+4j+c, same
//          per-r serial chains).
// Phase B: 16x16x32 bf16 MFMA, A[32][512] x B'[512][192]; wave w owns cols 48w..48w+47.
// Epilogue: stage out tile in LDS (reusing A), coalesced nontemporal f32x4 copy.
__global__ __launch_bounds__(256, 4) void fused_main_kernel(
    const float* __restrict__ x, const float* __restrict__ xvar,
    const float* __restrict__ gam, const float* __restrict__ bet,
    const float* __restrict__ eps_x,
    const ushort* __restrict__ Bp, const float* __restrict__ spc,
    float* __restrict__ out) {
  __shared__ ushort As[TM * 512];
  __shared__ float sxl[TM];
  const int tid = threadIdx.x;
  const int wave = tid >> 6;
  const int lane = tid & 63;
  const int64_t nbase = (int64_t)blockIdx.x * TM;

  // ---------------- Phase A ----------------
  const int sub = lane >> 4;  // row within group of 4
  const int l = lane & 15;    // 16 lanes per row, 16 elems each
  f32x4 gg[4], bb[4];
#pragma unroll
  for (int j = 0; j < 4; ++j) {
    gg[j] = *(const f32x4*)(gam + l * 16 + 4 * j);
    bb[j] = *(const f32x4*)(bet + l * 16 + 4 * j);
  }

  for (int g = 0; g < 2; ++g) {
    const int m = wave * 8 + g * 4 + sub;
    const int64_t n = nbase + m;
    const float* px = x + n * KD + l * 16;
    const float* pxv = xvar + n * KD + l * 16;
    f32x4 xm[4], xv[4];
#pragma unroll
    for (int j = 0; j < 4; ++j) {
      xm[j] = *(const f32x4*)(px + 4 * j);
      xv[j] = *(const f32x4*)(pxv + 4 * j);
    }
    // preload BOTH eps rows up front: r=1's loads fly under r=0's chains
    f32x4 ee[2][4];
#pragma unroll
    for (int r = 0; r < 2; ++r) {
      const float* pe = eps_x + ((int64_t)r * NPIX + n) * KD + l * 16;
#pragma unroll
      for (int j = 0; j < 4; ++j) ee[r][j] = *(const f32x4*)(pe + 4 * j);
    }
    float sxv = 0.f;
#pragma unroll
    for (int j = 0; j < 4; ++j) sxv += xv[j].x + xv[j].y + xv[j].z + xv[j].w;
    sxv = wred16(sxv);

    f32x4 acc[4];
#pragma unroll
    for (int j = 0; j < 4; ++j) acc[j] = (f32x4){0.f, 0.f, 0.f, 0.f};

#pragma unroll
    for (int r = 0; r < 2; ++r) {
      f32x4 v[4];
      float s1 = 0.f, s2 = 0.f;
#pragma unroll
      for (int j = 0; j < 4; ++j) {
        f32x4 e = ee[r][j];
        v[j].x = e.x * xv[j].x + xm[j].x;
        v[j].y = e.y * xv[j].y + xm[j].y;
        v[j].z = e.z * xv[j].z + xm[j].z;
        v[j].w = e.w * xv[j].w + xm[j].w;
        s1 += v[j].x + v[j].y + v[j].z + v[j].w;
        s2 += v[j].x * v[j].x + v[j].y * v[j].y + v[j].z * v[j].z + v[j].w * v[j].w;
      }
      s1 = wred16(s1);
      s2 = wred16(s2);
      float mean = s1 * (1.f / KD);
      float var = s2 * (1.f / KD) - mean * mean;
      float rs = rsqrtf(var + LN_EPS);
      float n2 = 0.f;
      f32x4 y[4];
#pragma unroll
      for (int j = 0; j < 4; ++j) {
        y[j].x = (v[j].x - mean) * rs * gg[j].x + bb[j].x;
        y[j].y = (v[j].y - mean) * rs * gg[j].y + bb[j].y;
        y[j].z = (v[j].z - mean) * rs * gg[j].z + bb[j].z;
        y[j].w = (v[j].w - mean) * rs * gg[j].w + bb[j].w;
        n2 += y[j].x * y[j].x + y[j].y * y[j].y + y[j].z * y[j].z + y[j].w * y[j].w;
      }
      n2 = wred16(n2);
      float inv = 1.f / fmaxf(sqrtf(n2), 1e-12f);
#pragma unroll
      for (int j = 0; j < 4; ++j) {
        acc[j].x += y[j].x * inv;
        acc[j].y += y[j].y * inv;
        acc[j].z += y[j].z * inv;
        acc[j].w += y[j].w * inv;
      }
    }

    // pack to bf16 and write swizzled LDS row m
    char* rowp = (char*)As + m * 1024;
    const int sw = (m & 7) << 4;  // XOR swizzle: 16B chunks spread across banks
    union {
      uint4 q;
      ushort s[8];
    } pk;
    // xbar half (scale 0.5 = mean over R=2)
    pk.s[0] = f2bf(0.5f * acc[0].x);
    pk.s[1] = f2bf(0.5f * acc[0].y);
    pk.s[2] = f2bf(0.5f * acc[0].z);
    pk.s[3] = f2bf(0.5f * acc[0].w);
    pk.s[4] = f2bf(0.5f * acc[1].x);
    pk.s[5] = f2bf(0.5f * acc[1].y);
    pk.s[6] = f2bf(0.5f * acc[1].z);
    pk.s[7] = f2bf(0.5f * acc[1].w);
    *(uint4*)(rowp + ((l * 32) ^ sw)) = pk.q;
    pk.s[0] = f2bf(0.5f * acc[2].x);
    pk.s[1] = f2bf(0.5f * acc[2].y);
    pk.s[2] = f2bf(0.5f * acc[2].z);
    pk.s[3] = f2bf(0.5f * acc[2].w);
    pk.s[4] = f2bf(0.5f * acc[3].x);
    pk.s[5] = f2bf(0.5f * acc[3].y);
    pk.s[6] = f2bf(0.5f * acc[3].z);
    pk.s[7] = f2bf(0.5f * acc[3].w);
    *(uint4*)(rowp + ((l * 32 + 16) ^ sw)) = pk.q;
    // sqrt(x_var) half
    pk.s[0] = f2bf(sqrtf(xv[0].x));
    pk.s[1] = f2bf(sqrtf(xv[0].y));
    pk.s[2] = f2bf(sqrtf(xv[0].z));
    pk.s[3] = f2bf(sqrtf(xv[0].w));
    pk.s[4] = f2bf(sqrtf(xv[1].x));
    pk.s[5] = f2bf(sqrtf(xv[1].y));
    pk.s[6] = f2bf(sqrtf(xv[1].z));
    pk.s[7] = f2bf(sqrtf(xv[1].w));
    *(uint4*)(rowp + ((512 + l * 32) ^ sw)) = pk.q;
    pk.s[0] = f2bf(sqrtf(xv[2].x));
    pk.s[1] = f2bf(sqrtf(xv[2].y));
    pk.s[2] = f2bf(sqrtf(xv[2].z));
    pk.s[3] = f2bf(sqrtf(xv[2].w));
    pk.s[4] = f2bf(sqrtf(xv[3].x));
    pk.s[5] = f2bf(sqrtf(xv[3].y));
    pk.s[6] = f2bf(sqrtf(xv[3].z));
    pk.s[7] = f2bf(sqrtf(xv[3].w));
    *(uint4*)(rowp + ((512 + l * 32 + 16) ^ sw)) = pk.q;
    if (l == 0) sxl[m] = LAMBDA * sxv;
  }
  __syncthreads();

  // ---------------- Phase B: MFMA ----------------
  f32x4 acc[2][3];
#pragma unroll
  for (int s = 0; s < 2; ++s)
#pragma unroll
    for (int t = 0; t < 3; ++t) acc[s][t] = (f32x4){0.f, 0.f, 0.f, 0.f};

  const int colq = lane & 15;
  const int kq = lane >> 4;
  const int colbase = wave * 48;
#pragma unroll
  for (int kk = 0; kk < 16; ++kk) {
    const int kbyte = kk * 64 + kq * 16;
    bf16x8 af[2];
#pragma unroll
    for (int s = 0; s < 2; ++s) {
      const int m = s * 16 + colq;
      af[s] = *(const bf16x8*)((const char*)As + m * 1024 + (kbyte ^ ((m & 7) << 4)));
    }
#pragma unroll
    for (int t = 0; t < 3; ++t) {
      const int cmc = colbase + t * 16 + colq;
      bf16x8 bfr = *(const bf16x8*)((const char*)Bp + (size_t)cmc * 1024 + kbyte);
#pragma unroll
      for (int s = 0; s < 2; ++s)
        acc[s][t] = __builtin_amdgcn_mfma_f32_16x16x32_bf16(af[s], bfr, acc[s][t], 0, 0, 0);
    }
  }
  __syncthreads();  // all As reads done before reuse

  // ---------------- Epilogue: stage in LDS, coalesced NT copy ----------------
  float* st = (float*)As;  // 32*190 floats = 24320 B <= 32 KB
#pragma unroll
  for (int t = 0; t < 3; ++t) {
    const int col = colbase + t * 16 + colq;
    if (col < NCM) {
      const float sc = spc[col];
#pragma unroll
      for (int s = 0; s < 2; ++s) {
#pragma unroll
        for (int j = 0; j < 4; ++j) {
          const int m = s * 16 + kq * 4 + j;
          st[m * NCM + col] = acc[s][t][j] - sc - sxl[m];
        }
      }
    }
  }
  __syncthreads();
  float* dst = out + nbase * NCM;
  const f32x4* src = (const f32x4*)st;
  for (int i = tid; i < TM * NCM / 4; i += 256) {  // 1520 f32x4
    f32x4 v = src[i];
    __builtin_nontemporal_store(v, (f32x4*)dst + i);
  }
}

extern "C" void kernel_launch(void* const* d_in, const int* in_sizes, int n_in,
                              void* d_out, int out_size, void* d_ws, size_t ws_size,
                              hipStream_t stream) {
  const float* x = (const float*)d_in[0];
  const float* x_var = (const float*)d_in[1];
  const float* protos = (const float*)d_in[2];
  const float* pvar = (const float*)d_in[3];
  const float* gam = (const float*)d_in[4];
  const float* bet = (const float*)d_in[5];
  const float* eps_x = (const float*)d_in[6];
  const float* eps_p = (const float*)d_in[7];
  float* out = (float*)d_out;

  ushort* Bp = (ushort*)d_ws;                          // 192*512*2 = 196608 B
  float* spc = (float*)((char*)d_ws + CMP * 512 * 2);  // 192*4 B

  proto_prep_kernel<<<CMP / 4, 256, 0, stream>>>(protos, pvar, gam, bet, eps_p, Bp, spc);
  fused_main_kernel<<<NPIX / TM, 256, 0, stream>>>(x, x_var, gam, bet, eps_x, Bp, spc, out);
}